// Round 15
// baseline (537.509 us; speedup 1.0000x reference)
//
#include <hip/hip_runtime.h>

// B=2, H=256, W=448. bf16 MFMA convs + MFMA cost volume.
// Round 15: r12 structure (best, 488us) + COUT-split occupancy boost on the
// two 128-out convs. Evidence r13 (fewer LDS loads: neutral) + r14 (bigger
// bursts at 2 waves/SIMD: regression) says the conv plateau is latency
// coverage = waves/SIMD. Splitting COUT 128 -> 2x64 halves the accumulator
// (64->32 AGPR) so rconv1/rconv2 run 5-6 waves/SIMD instead of 4.
#define HH 256
#define WW 448
#define HW (HH * WW)

typedef short bf16x8 __attribute__((ext_vector_type(8)));
typedef float f32x4 __attribute__((ext_vector_type(4)));
typedef unsigned int uint32;
typedef unsigned short ushort;

__device__ __forceinline__ ushort f2bf(float f) {
    uint32 u = __float_as_uint(f);
    u += 0x7fffu + ((u >> 16) & 1u);  // RNE
    return (ushort)(u >> 16);
}

// ---------------------------------------------------------------------------
// Weight repack (all 5 convs in one kernel): fp32 OIHW -> bf16 [tap][kc][n][32]
// ---------------------------------------------------------------------------
__device__ __forceinline__ void pack_one(
    int i, const float* __restrict__ w, ushort* __restrict__ wp,
    int CinReal, int CinPad, int Cout)
{
    int total = 9 * CinPad * Cout;
    if (i >= total) return;
    int ci = i & 31;
    int rest = i >> 5;
    int n = rest % Cout;
    int rest2 = rest / Cout;
    int KC = CinPad / 32;
    int kc = rest2 % KC;
    int tap = rest2 / KC;
    int cin = kc * 32 + ci;
    float v = (cin < CinReal) ? w[((size_t)n * CinReal + cin) * 9 + tap] : 0.f;
    wp[i] = f2bf(v);
}

__global__ __launch_bounds__(256) void pack_all_k(
    const float* fW2, const float* fW3, const float* rW1,
    const float* rW2, const float* rW3,
    ushort* wp2, ushort* wp3, ushort* wpr1, ushort* wpr2, ushort* wpr3)
{
    int i = blockIdx.x * 256 + threadIdx.x;
    pack_one(i, fW2, wp2, 64, 64, 64);
    pack_one(i, fW3, wp3, 64, 64, 32);
    pack_one(i, rW1, wpr1, 83, 96, 128);
    pack_one(i, rW2, wpr2, 128, 128, 128);
    pack_one(i, rW3, wpr3, 128, 128, 64);
}

// ---------------------------------------------------------------------------
// MFMA implicit-GEMM 3x3 SAME conv. NHWC bf16 in/out, fp32 bias, optional
// ReLU. Block 256 = 4 waves; tile = 8 rows x 16 cols = 128 px. Cin staged
// in 64-channel phases (LDS 25.9 KB). grid.z = slice*CGRP + cout-group.
// CGRP splits COUT into groups (halved accumulator -> higher occupancy);
// wave tiling on the group size: 128 -> MG1/NG4 (WM8,WN2);
// 64 -> MG2/NG2 (WM4,WN2); 32 -> MG2/NG2 (WM4,WN1).
// ---------------------------------------------------------------------------
template <int CIN, int COUT, int CGRP, int RELU>
__global__ __launch_bounds__(256, (CGRP > 1 ? 5 : 4)) void convmfma_k(
    const ushort* __restrict__ in, const ushort* __restrict__ wp,
    const float* __restrict__ bias, ushort* __restrict__ out,
    long inStride, long outStride)
{
    constexpr int KC = CIN / 32;
    constexpr int NPH = (CIN + 63) / 64;
    constexpr int CS = 72;
    constexpr int COUTG = COUT / CGRP;
    constexpr int NG = (COUTG >= 128) ? 4 : 2;
    constexpr int WN = (COUTG / 16) / NG;
    constexpr int MG = 4 / NG;
    constexpr int WM = 8 / MG;

    __shared__ __align__(16) ushort lds[180 * CS];

    const int tid = threadIdx.x;
    const int x0 = blockIdx.x * 16;
    const int y0 = blockIdx.y * 8;
    const int cg = blockIdx.z % CGRP;
    const int slice = blockIdx.z / CGRP;
    in += (size_t)slice * inStride;
    out += (size_t)slice * outStride;

    const int wv = tid >> 6;
    const int lane = tid & 63;
    const int m = lane & 15;
    const int quad = lane >> 4;
    const int mbase = (wv % MG) * WM;
    const int nbase = cg * COUTG + (wv / MG) * WN * 16;  // absolute cout base

    const ushort* ldsA = lds + (mbase * 18 + m) * CS + quad * 8;
    const ushort* wpB = wp + ((size_t)nbase + m) * 32 + quad * 8;

    f32x4 acc[WM][WN];
#pragma unroll
    for (int t = 0; t < WM; ++t)
#pragma unroll
        for (int u = 0; u < WN; ++u)
            acc[t][u] = (f32x4){0.f, 0.f, 0.f, 0.f};

#pragma unroll 1
    for (int ph = 0; ph < NPH; ++ph) {
        const int C = (CIN - ph * 64 >= 64) ? 64 : (CIN - ph * 64);
        const int sh = (C == 64) ? 3 : 2;
        const int ch8 = C >> 3;

        if (ph) __syncthreads();
        for (int i = tid; i < 180 * ch8; i += 256) {
            int p = i >> sh, c8 = i & (ch8 - 1);
            int ry = p / 18, rx = p - ry * 18;
            int gy = y0 + ry - 1, gx = x0 + rx - 1;
            float4 v = make_float4(0.f, 0.f, 0.f, 0.f);
            if (gy >= 0 && gy < HH && gx >= 0 && gx < WW)
                v = *(const float4*)(in + ((size_t)gy * WW + gx) * CIN + ph * 64 + c8 * 8);
            *(float4*)(lds + p * CS + c8 * 8) = v;
        }
        __syncthreads();

        const int KCc = C / 32;
        const ushort* wpP = wpB + (size_t)(ph * 2) * COUT * 32;
#pragma unroll 1
        for (int tap = 0; tap < 9; ++tap) {
            const int ky = tap / 3;
            const int kx = tap - 3 * ky;
            const ushort* wpT = wpP + (size_t)tap * KC * COUT * 32;
#pragma unroll
            for (int kc = 0; kc < 2; ++kc) {
                if (kc >= KCc) break;
                bf16x8 b[WN];
#pragma unroll
                for (int u = 0; u < WN; ++u)
                    b[u] = *(const bf16x8*)(wpT + ((size_t)kc * COUT + u * 16) * 32);
#pragma unroll
                for (int th = 0; th < WM / 4; ++th) {
                    bf16x8 a[4];
#pragma unroll
                    for (int t4 = 0; t4 < 4; ++t4)
                        a[t4] = *(const bf16x8*)(ldsA +
                                ((th * 4 + t4 + ky) * 18 + kx) * CS + kc * 32);
#pragma unroll
                    for (int t4 = 0; t4 < 4; ++t4)
#pragma unroll
                        for (int u = 0; u < WN; ++u)
                            acc[th * 4 + t4][u] =
                                __builtin_amdgcn_mfma_f32_16x16x32_bf16(
                                    a[t4], b[u], acc[th * 4 + t4][u], 0, 0, 0);
                }
            }
        }
    }

#pragma unroll
    for (int u = 0; u < WN; ++u) {
        const int n = nbase + u * 16 + m;
        const float bs = bias[n];
#pragma unroll
        for (int t = 0; t < WM; ++t) {
            const int y = y0 + mbase + t;
#pragma unroll
            for (int r = 0; r < 4; ++r) {
                const int x = x0 + quad * 4 + r;
                float v = acc[t][u][r] + bs;
                if (RELU) v = fmaxf(v, 0.f);
                out[((size_t)y * WW + x) * COUT + n] = f2bf(v);
            }
        }
    }
}

// ---------------------------------------------------------------------------
// fconv1: fp32 NCHW (3,H,W) -> bf16 NHWC 64ch, ReLU.
// grid.z = slice: img = z&1 (0 -> feat1 src, 1 -> feat2 src), b = z>>1.
// ---------------------------------------------------------------------------
__global__ __launch_bounds__(256) void fconv1_k(
    const float* __restrict__ f1src, const float* __restrict__ f2src,
    const float* __restrict__ w, const float* __restrict__ bias,
    ushort* __restrict__ out, long inStride, long outStride)
{
    __shared__ float wl[1728];
    __shared__ float patch[3][4][18];
    const int tid = threadIdx.x;
    const int x0 = blockIdx.x * 16, y0 = blockIdx.y * 2;
    const int z = blockIdx.z;
    const float* in = ((z & 1) ? f2src : f1src) + (size_t)(z >> 1) * inStride;
    out += (size_t)z * outStride;
    for (int i = tid; i < 1728; i += 256) wl[i] = w[i];
    for (int i = tid; i < 216; i += 256) {
        int ci = i / 72;
        int r = (i - ci * 72) / 18;
        int c = i - ci * 72 - r * 18;
        int gy = y0 + r - 1, gx = x0 + c - 1;
        patch[ci][r][c] = (gy >= 0 && gy < HH && gx >= 0 && gx < WW)
                              ? in[(size_t)ci * HW + gy * WW + gx] : 0.f;
    }
    __syncthreads();
    const int g = tid & 7;
    const int p = tid >> 3;
    const int py = p >> 4, px = p & 15;
    float acc[8];
#pragma unroll
    for (int j = 0; j < 8; ++j) acc[j] = bias[g * 8 + j];
#pragma unroll
    for (int ci = 0; ci < 3; ++ci)
#pragma unroll
        for (int k = 0; k < 9; ++k) {
            const int ky = k / 3, kx = k - 3 * ky;
            const float v = patch[ci][py + ky][px + kx];
#pragma unroll
            for (int j = 0; j < 8; ++j)
                acc[j] = fmaf(v, wl[(g * 8 + j) * 27 + ci * 9 + k], acc[j]);
        }
    ushort ov[8];
#pragma unroll
    for (int j = 0; j < 8; ++j) ov[j] = f2bf(fmaxf(acc[j], 0.f));
    const int y = y0 + py, x = x0 + px;
    *(float4*)(out + ((size_t)y * WW + x) * 64 + g * 8) = *(const float4*)ov;
}

// ---------------------------------------------------------------------------
// Bilinear warp, border padding, align_corners=True. NHWC bf16 32ch.
// grid.y = batch.
// ---------------------------------------------------------------------------
__global__ __launch_bounds__(256) void warp_k(
    const ushort* __restrict__ f2, const float* __restrict__ flow,
    ushort* __restrict__ outp, long fStride, long flowStride, long oStride)
{
    int idx = blockIdx.x * 256 + threadIdx.x;
    if (idx >= HW) return;
    f2 += (size_t)blockIdx.y * fStride;
    flow += (size_t)blockIdx.y * flowStride;
    outp += (size_t)blockIdx.y * oStride;
    int y = idx / WW, x = idx - y * WW;
    float px_ = (float)x + flow[idx];
    float py_ = (float)y + flow[idx + HW];
    px_ = fminf(fmaxf(px_, 0.f), (float)(WW - 1));
    py_ = fminf(fmaxf(py_, 0.f), (float)(HH - 1));
    float fx0 = floorf(px_), fy0 = floorf(py_);
    int xi0 = (int)fx0, yi0 = (int)fy0;
    int xi1 = min(xi0 + 1, WW - 1), yi1 = min(yi0 + 1, HH - 1);
    float wx = px_ - fx0, wy = py_ - fy0;
    float w00 = (1.f - wx) * (1.f - wy), w01 = wx * (1.f - wy);
    float w10 = (1.f - wx) * wy, w11 = wx * wy;

    const uint32* a = (const uint32*)(f2 + ((size_t)yi0 * WW + xi0) * 32);
    const uint32* b = (const uint32*)(f2 + ((size_t)yi0 * WW + xi1) * 32);
    const uint32* c = (const uint32*)(f2 + ((size_t)yi1 * WW + xi0) * 32);
    const uint32* d = (const uint32*)(f2 + ((size_t)yi1 * WW + xi1) * 32);
    uint32 ov[16];
#pragma unroll
    for (int i = 0; i < 16; ++i) {
        uint32 wa = a[i], wb = b[i], wc = c[i], wd = d[i];
        float lo = __uint_as_float(wa << 16) * w00 + __uint_as_float(wb << 16) * w01 +
                   __uint_as_float(wc << 16) * w10 + __uint_as_float(wd << 16) * w11;
        float hi = __uint_as_float(wa & 0xffff0000u) * w00 + __uint_as_float(wb & 0xffff0000u) * w01 +
                   __uint_as_float(wc & 0xffff0000u) * w10 + __uint_as_float(wd & 0xffff0000u) * w11;
        ov[i] = ((uint32)f2bf(hi) << 16) | f2bf(lo);
    }
    uint32* o = (uint32*)(outp + (size_t)idx * 32);
#pragma unroll
    for (int i = 0; i < 16; ++i) o[i] = ov[i];
}

// ---------------------------------------------------------------------------
// Cost volume via MFMA. Block 256 = 4 waves; wave wv handles one y-row
// (y = blockIdx.y*4 + wv) x 16-px tile x all 9 dy. Two 16x16x32 GEMMs per dy.
// grid.z = batch (separate strides per buffer).
// ---------------------------------------------------------------------------
__global__ __launch_bounds__(256) void cost_mfma_k(
    const ushort* __restrict__ f1, const ushort* __restrict__ f2w,
    const float* __restrict__ flow, ushort* __restrict__ hb,
    long f1S, long f2wS, long hbS, long flowS)
{
    const int tid = threadIdx.x;
    const int wv = tid >> 6;
    const int lane = tid & 63;
    const int c = lane & 15;
    const int quad = lane >> 4;
    const int x0 = blockIdx.x * 16;
    const int y = blockIdx.y * 4 + wv;
    f1 += (size_t)blockIdx.z * f1S;
    f2w += (size_t)blockIdx.z * f2wS;
    hb += (size_t)blockIdx.z * hbS;
    flow += (size_t)blockIdx.z * flowS;

    const bf16x8 a = *(const bf16x8*)(f1 + ((size_t)y * WW + x0 + c) * 32 + quad * 8);

    const int xc0 = min(max(x0 - 4 + c, 0), WW - 1);
    const int xc1 = min(max(x0 + 12 + c, 0), WW - 1);

    ushort* hrow = hb + ((size_t)y * WW + x0) * 96;

#pragma unroll 1
    for (int dyi = 0; dyi < 9; ++dyi) {
        const int ys = min(max(y + dyi - 4, 0), HH - 1);
        const bf16x8 b0 = *(const bf16x8*)(f2w + ((size_t)ys * WW + xc0) * 32 + quad * 8);
        const bf16x8 b1 = *(const bf16x8*)(f2w + ((size_t)ys * WW + xc1) * 32 + quad * 8);
        f32x4 s0 = __builtin_amdgcn_mfma_f32_16x16x32_bf16(
            a, b0, (f32x4){0.f, 0.f, 0.f, 0.f}, 0, 0, 0);
        f32x4 s1 = __builtin_amdgcn_mfma_f32_16x16x32_bf16(
            a, b1, (f32x4){0.f, 0.f, 0.f, 0.f}, 0, 0, 0);

        ushort* hq = hrow + dyi * 9;
#pragma unroll
        for (int r = 0; r < 4; ++r) {
            const int m = quad * 4 + r;
            const int d0 = c - m;
            const int d1 = c + 16 - m;
            if (d0 >= 0 && d0 <= 8) hq[(size_t)m * 96 + d0] = f2bf(s0[r]);
            if (d1 <= 8) hq[(size_t)m * 96 + d1] = f2bf(s1[r]);
        }
    }

    if (lane < 16) {
        const int px = y * WW + x0 + lane;
        ushort* hq = hb + (size_t)px * 96;
        hq[81] = f2bf(flow[px]);
        hq[82] = f2bf(flow[px + HW]);
#pragma unroll
        for (int ch = 83; ch < 96; ++ch) hq[ch] = 0;
    }
}

// ---------------------------------------------------------------------------
// rconv4: 64 -> 2, + initial_flow residual, fp32 NCHW output. grid.y = batch.
// ---------------------------------------------------------------------------
__global__ __launch_bounds__(256) void rconv4_k(
    const ushort* __restrict__ in, const float* __restrict__ w,
    const float* __restrict__ bias, const float* __restrict__ flow,
    float* __restrict__ out, long inStride, long ioStride)
{
    __shared__ float wl[1152];
    for (int i = threadIdx.x; i < 1152; i += 256) wl[i] = w[i];
    __syncthreads();
    in += (size_t)blockIdx.y * inStride;
    flow += (size_t)blockIdx.y * ioStride;
    out += (size_t)blockIdx.y * ioStride;
    int px = blockIdx.x * 256 + threadIdx.x;
    if (px >= HW) return;
    int y = px / WW, x = px - y * WW;
    float a0 = bias[0], a1 = bias[1];
    for (int ky = 0; ky < 3; ++ky) {
        int gy = y + ky - 1;
        if (gy < 0 || gy >= HH) continue;
        for (int kx = 0; kx < 3; ++kx) {
            int gx = x + kx - 1;
            if (gx < 0 || gx >= WW) continue;
            const uint32* p = (const uint32*)(in + ((size_t)gy * WW + gx) * 64);
            int tap = ky * 3 + kx;
#pragma unroll
            for (int i = 0; i < 32; ++i) {
                uint32 wv = p[i];
                float lo = __uint_as_float(wv << 16);
                float hi = __uint_as_float(wv & 0xffff0000u);
                a0 = fmaf(lo, wl[(2 * i) * 9 + tap], a0);
                a0 = fmaf(hi, wl[(2 * i + 1) * 9 + tap], a0);
                a1 = fmaf(lo, wl[576 + (2 * i) * 9 + tap], a1);
                a1 = fmaf(hi, wl[576 + (2 * i + 1) * 9 + tap], a1);
            }
        }
    }
    out[px] = flow[px] + a0;
    out[px + HW] = flow[px + HW] + a1;
}

extern "C" void kernel_launch(void* const* d_in, const int* in_sizes, int n_in,
                              void* d_out, int out_size, void* d_ws, size_t ws_size,
                              hipStream_t stream)
{
    (void)in_sizes; (void)n_in; (void)out_size;
    const float* feat1 = (const float*)d_in[0];
    const float* feat2 = (const float*)d_in[1];
    const float* iflow = (const float*)d_in[2];
    const float* fW1 = (const float*)d_in[3];  const float* fb1 = (const float*)d_in[4];
    const float* fW2 = (const float*)d_in[5];  const float* fb2 = (const float*)d_in[6];
    const float* fW3 = (const float*)d_in[7];  const float* fb3 = (const float*)d_in[8];
    const float* rW1 = (const float*)d_in[9];  const float* rb1 = (const float*)d_in[10];
    const float* rW2 = (const float*)d_in[11]; const float* rb2 = (const float*)d_in[12];
    const float* rW3 = (const float*)d_in[13]; const float* rb3 = (const float*)d_in[14];
    const float* rW4 = (const float*)d_in[15]; const float* rb4 = (const float*)d_in[16];
    float* out = (float*)d_out;

    // Workspace (bf16 elems): [packed weights][XA nb*128P][XB nb*128P][F nb*64P]
    // Aliases: F2W = XA (nb*32P), Hb = XA+nb*32P (nb*96P), R1 = XB,
    // R2 = XA, R3 = F. Live ranges disjoint.
    const size_t P = (size_t)HW;
    const size_t WTOT = (size_t)9 * (64 * 64 + 64 * 32 + 96 * 128 + 128 * 128 + 128 * 64);
    ushort* ws0 = (ushort*)d_ws;
    ushort* wp2  = ws0;
    ushort* wp3  = wp2 + 9 * 64 * 64;
    ushort* wpr1 = wp3 + 9 * 64 * 32;
    ushort* wpr2 = wpr1 + 9 * 96 * 128;
    ushort* wpr3 = wpr2 + 9 * 128 * 128;
    ushort* arena = ws0 + WTOT;

    const bool merged = ws_size >= (WTOT + 640 * P) * sizeof(ushort);
    const int nb = merged ? 2 : 1;
    const int nloop = merged ? 1 : 2;

    ushort* XA = arena;
    ushort* XB = XA + (size_t)(nb * 128) * P;
    ushort* F  = XB + (size_t)(nb * 128) * P;
    ushort* F2W = XA;
    ushort* Hb  = XA + (size_t)(nb * 32) * P;
    ushort* R1  = XB;
    ushort* R2  = XA;
    ushort* R3  = F;

    const dim3 blk(256);
    pack_all_k<<<dim3((9 * 128 * 128 + 255) / 256), blk, 0, stream>>>(
        fW2, fW3, rW1, rW2, rW3, wp2, wp3, wpr1, wpr2, wpr3);

    const dim3 gConvX(WW / 16, HH / 8, nb * 2);   // extractor convs (b x img)
    const dim3 gConvB(WW / 16, HH / 8, nb);       // head convs, CGRP=1
    const dim3 gConvS(WW / 16, HH / 8, nb * 2);   // head convs, CGRP=2 (b x cg)
    const dim3 gF1(WW / 16, HH / 2, nb * 2);
    const dim3 gCost(WW / 16, HH / 4, nb);
    const int gPix = (HW + 255) / 256;

    for (int lb = 0; lb < nloop; ++lb) {
        const float* f1in = feat1 + (size_t)lb * 3 * P;
        const float* f2in = feat2 + (size_t)lb * 3 * P;
        const float* flw  = iflow + (size_t)lb * 2 * P;
        float* outb = out + (size_t)lb * 2 * P;

        // Extractor, both images fused (z = b*2+img)
        fconv1_k<<<gF1, blk, 0, stream>>>(f1in, f2in, fW1, fb1, XA, 3 * (long)P, 64 * (long)P);
        convmfma_k<64, 64, 1, 1><<<gConvX, blk, 0, stream>>>(XA, wp2, fb2, XB, 64 * (long)P, 64 * (long)P);
        convmfma_k<64, 32, 1, 1><<<gConvX, blk, 0, stream>>>(XB, wp3, fb3, F, 64 * (long)P, 32 * (long)P);

        // Warp f2 features (F2[b] = F + (2b+1)*32P, batch stride 64P)
        warp_k<<<dim3(gPix, nb), blk, 0, stream>>>(F + 32 * P, flw, F2W,
                                                   64 * (long)P, 2 * (long)P, 32 * (long)P);

        // Cost volume (+ flow + zero pad) -> Hb (96ch NHWC)
        cost_mfma_k<<<gCost, blk, 0, stream>>>(F, F2W, flw, Hb,
                                               64 * (long)P, 32 * (long)P, 96 * (long)P, 2 * (long)P);

        // Refinement head: 128-out convs split into 2 cout-groups (occupancy)
        convmfma_k<96, 128, 2, 1><<<gConvS, blk, 0, stream>>>(Hb, wpr1, rb1, R1, 96 * (long)P, 128 * (long)P);
        convmfma_k<128, 128, 2, 1><<<gConvS, blk, 0, stream>>>(R1, wpr2, rb2, R2, 128 * (long)P, 128 * (long)P);
        convmfma_k<128, 64, 1, 1><<<gConvB, blk, 0, stream>>>(R2, wpr3, rb3, R3, 128 * (long)P, 64 * (long)P);
        rconv4_k<<<dim3(gPix, nb), blk, 0, stream>>>(R3, rW4, rb4, flw, outb, 64 * (long)P, 2 * (long)P);
    }
}

// Round 16
// 467.053 us; speedup vs baseline: 1.1509x; 1.1509x over previous
//
#include <hip/hip_runtime.h>

// B=2, H=256, W=448. bf16 MFMA convs + MFMA cost volume.
// Round 16: r12 structure (best, 488us) + XOR-swizzled conv LDS (CS=64,
// slot = g ^ (p&7)). r12's CS=72 pad gave stride 36 dwords -> 8-way bank
// aliasing, 8.26e6 conflict cycles = ~17% of conv time. Swizzle keeps all
// b128 accesses 16B-aligned and reduces aliasing to 2-way (free).
#define HH 256
#define WW 448
#define HW (HH * WW)

typedef short bf16x8 __attribute__((ext_vector_type(8)));
typedef float f32x4 __attribute__((ext_vector_type(4)));
typedef unsigned int uint32;
typedef unsigned short ushort;

__device__ __forceinline__ ushort f2bf(float f) {
    uint32 u = __float_as_uint(f);
    u += 0x7fffu + ((u >> 16) & 1u);  // RNE
    return (ushort)(u >> 16);
}

// ---------------------------------------------------------------------------
// Weight repack (all 5 convs in one kernel): fp32 OIHW -> bf16 [tap][kc][n][32]
// ---------------------------------------------------------------------------
__device__ __forceinline__ void pack_one(
    int i, const float* __restrict__ w, ushort* __restrict__ wp,
    int CinReal, int CinPad, int Cout)
{
    int total = 9 * CinPad * Cout;
    if (i >= total) return;
    int ci = i & 31;
    int rest = i >> 5;
    int n = rest % Cout;
    int rest2 = rest / Cout;
    int KC = CinPad / 32;
    int kc = rest2 % KC;
    int tap = rest2 / KC;
    int cin = kc * 32 + ci;
    float v = (cin < CinReal) ? w[((size_t)n * CinReal + cin) * 9 + tap] : 0.f;
    wp[i] = f2bf(v);
}

__global__ __launch_bounds__(256) void pack_all_k(
    const float* fW2, const float* fW3, const float* rW1,
    const float* rW2, const float* rW3,
    ushort* wp2, ushort* wp3, ushort* wpr1, ushort* wpr2, ushort* wpr3)
{
    int i = blockIdx.x * 256 + threadIdx.x;
    pack_one(i, fW2, wp2, 64, 64, 64);
    pack_one(i, fW3, wp3, 64, 64, 32);
    pack_one(i, rW1, wpr1, 83, 96, 128);
    pack_one(i, rW2, wpr2, 128, 128, 128);
    pack_one(i, rW3, wpr3, 128, 128, 64);
}

// ---------------------------------------------------------------------------
// MFMA implicit-GEMM 3x3 SAME conv. NHWC bf16 in/out, fp32 bias, optional
// ReLU. Block 256 = 4 waves; tile = 8 rows x 16 cols = 128 px. Cin staged
// in 64-channel phases. LDS layout: pixel p (10x18 halo), 8-short channel
// group g stored at slot g^(p&7) (XOR swizzle, CS=64 shorts/pixel, all
// accesses 16B-aligned, 2-way max bank aliasing). grid.z = slice.
// Wave tiling (measured optimum): COUT=128 -> MG1/NG4 (WM8,WN2);
// COUT=64 -> MG2/NG2 (WM4,WN2); COUT=32 -> MG2/NG2 (WM4,WN1).
// ---------------------------------------------------------------------------
template <int CIN, int COUT, int RELU>
__global__ __launch_bounds__(256, 4) void convmfma_k(
    const ushort* __restrict__ in, const ushort* __restrict__ wp,
    const float* __restrict__ bias, ushort* __restrict__ out,
    long inStride, long outStride)
{
    constexpr int KC = CIN / 32;
    constexpr int NPH = (CIN + 63) / 64;
    constexpr int NG = (COUT >= 128) ? 4 : 2;
    constexpr int WN = (COUT / 16) / NG;
    constexpr int MG = 4 / NG;
    constexpr int WM = 8 / MG;

    __shared__ __align__(16) ushort lds[180 * 64];  // 23 KB

    const int tid = threadIdx.x;
    const int x0 = blockIdx.x * 16;
    const int y0 = blockIdx.y * 8;
    in += (size_t)blockIdx.z * inStride;
    out += (size_t)blockIdx.z * outStride;

    const int wv = tid >> 6;
    const int lane = tid & 63;
    const int m = lane & 15;
    const int quad = lane >> 4;
    const int mbase = (wv % MG) * WM;
    const int nbase = (wv / MG) * WN * 16;

    const ushort* wpB = wp + ((size_t)nbase + m) * 32 + quad * 8;

    f32x4 acc[WM][WN];
#pragma unroll
    for (int t = 0; t < WM; ++t)
#pragma unroll
        for (int u = 0; u < WN; ++u)
            acc[t][u] = (f32x4){0.f, 0.f, 0.f, 0.f};

#pragma unroll 1
    for (int ph = 0; ph < NPH; ++ph) {
        const int C = (CIN - ph * 64 >= 64) ? 64 : (CIN - ph * 64);  // 64|32
        const int sh = (C == 64) ? 3 : 2;
        const int ch8 = C >> 3;

        if (ph) __syncthreads();
        for (int i = tid; i < 180 * ch8; i += 256) {
            int p = i >> sh, c8 = i & (ch8 - 1);
            int ry = p / 18, rx = p - ry * 18;
            int gy = y0 + ry - 1, gx = x0 + rx - 1;
            float4 v = make_float4(0.f, 0.f, 0.f, 0.f);
            if (gy >= 0 && gy < HH && gx >= 0 && gx < WW)
                v = *(const float4*)(in + ((size_t)gy * WW + gx) * CIN + ph * 64 + c8 * 8);
            *(float4*)(lds + p * 64 + ((c8 ^ (p & 7)) * 8)) = v;
        }
        __syncthreads();

        const int KCc = C / 32;
        const ushort* wpP = wpB + (size_t)(ph * 2) * COUT * 32;
#pragma unroll 1
        for (int tap = 0; tap < 9; ++tap) {
            const int ky = tap / 3;
            const int kx = tap - 3 * ky;
            const ushort* wpT = wpP + (size_t)tap * KC * COUT * 32;
            const int pBase = (mbase + ky) * 18 + m + kx;  // pixel idx, row t=0
#pragma unroll
            for (int kc = 0; kc < 2; ++kc) {
                if (kc >= KCc) break;
                const int g = kc * 4 + quad;  // 8-short channel group
                bf16x8 b[WN];
#pragma unroll
                for (int u = 0; u < WN; ++u)
                    b[u] = *(const bf16x8*)(wpT + ((size_t)kc * COUT + u * 16) * 32);
#pragma unroll
                for (int th = 0; th < WM / 4; ++th) {
                    bf16x8 a[4];
#pragma unroll
                    for (int t4 = 0; t4 < 4; ++t4) {
                        const int pA = pBase + (th * 4 + t4) * 18;
                        a[t4] = *(const bf16x8*)(lds + pA * 64 + ((g ^ (pA & 7)) * 8));
                    }
#pragma unroll
                    for (int t4 = 0; t4 < 4; ++t4)
#pragma unroll
                        for (int u = 0; u < WN; ++u)
                            acc[th * 4 + t4][u] =
                                __builtin_amdgcn_mfma_f32_16x16x32_bf16(
                                    a[t4], b[u], acc[th * 4 + t4][u], 0, 0, 0);
                }
            }
        }
    }

#pragma unroll
    for (int u = 0; u < WN; ++u) {
        const int n = nbase + u * 16 + m;
        const float bs = bias[n];
#pragma unroll
        for (int t = 0; t < WM; ++t) {
            const int y = y0 + mbase + t;
#pragma unroll
            for (int r = 0; r < 4; ++r) {
                const int x = x0 + quad * 4 + r;
                float v = acc[t][u][r] + bs;
                if (RELU) v = fmaxf(v, 0.f);
                out[((size_t)y * WW + x) * COUT + n] = f2bf(v);
            }
        }
    }
}

// ---------------------------------------------------------------------------
// fconv1: fp32 NCHW (3,H,W) -> bf16 NHWC 64ch, ReLU.
// grid.z = slice: img = z&1 (0 -> feat1 src, 1 -> feat2 src), b = z>>1.
// ---------------------------------------------------------------------------
__global__ __launch_bounds__(256) void fconv1_k(
    const float* __restrict__ f1src, const float* __restrict__ f2src,
    const float* __restrict__ w, const float* __restrict__ bias,
    ushort* __restrict__ out, long inStride, long outStride)
{
    __shared__ float wl[1728];
    __shared__ float patch[3][4][18];
    const int tid = threadIdx.x;
    const int x0 = blockIdx.x * 16, y0 = blockIdx.y * 2;
    const int z = blockIdx.z;
    const float* in = ((z & 1) ? f2src : f1src) + (size_t)(z >> 1) * inStride;
    out += (size_t)z * outStride;
    for (int i = tid; i < 1728; i += 256) wl[i] = w[i];
    for (int i = tid; i < 216; i += 256) {
        int ci = i / 72;
        int r = (i - ci * 72) / 18;
        int c = i - ci * 72 - r * 18;
        int gy = y0 + r - 1, gx = x0 + c - 1;
        patch[ci][r][c] = (gy >= 0 && gy < HH && gx >= 0 && gx < WW)
                              ? in[(size_t)ci * HW + gy * WW + gx] : 0.f;
    }
    __syncthreads();
    const int g = tid & 7;
    const int p = tid >> 3;
    const int py = p >> 4, px = p & 15;
    float acc[8];
#pragma unroll
    for (int j = 0; j < 8; ++j) acc[j] = bias[g * 8 + j];
#pragma unroll
    for (int ci = 0; ci < 3; ++ci)
#pragma unroll
        for (int k = 0; k < 9; ++k) {
            const int ky = k / 3, kx = k - 3 * ky;
            const float v = patch[ci][py + ky][px + kx];
#pragma unroll
            for (int j = 0; j < 8; ++j)
                acc[j] = fmaf(v, wl[(g * 8 + j) * 27 + ci * 9 + k], acc[j]);
        }
    ushort ov[8];
#pragma unroll
    for (int j = 0; j < 8; ++j) ov[j] = f2bf(fmaxf(acc[j], 0.f));
    const int y = y0 + py, x = x0 + px;
    *(float4*)(out + ((size_t)y * WW + x) * 64 + g * 8) = *(const float4*)ov;
}

// ---------------------------------------------------------------------------
// Bilinear warp, border padding, align_corners=True. NHWC bf16 32ch.
// grid.y = batch.
// ---------------------------------------------------------------------------
__global__ __launch_bounds__(256) void warp_k(
    const ushort* __restrict__ f2, const float* __restrict__ flow,
    ushort* __restrict__ outp, long fStride, long flowStride, long oStride)
{
    int idx = blockIdx.x * 256 + threadIdx.x;
    if (idx >= HW) return;
    f2 += (size_t)blockIdx.y * fStride;
    flow += (size_t)blockIdx.y * flowStride;
    outp += (size_t)blockIdx.y * oStride;
    int y = idx / WW, x = idx - y * WW;
    float px_ = (float)x + flow[idx];
    float py_ = (float)y + flow[idx + HW];
    px_ = fminf(fmaxf(px_, 0.f), (float)(WW - 1));
    py_ = fminf(fmaxf(py_, 0.f), (float)(HH - 1));
    float fx0 = floorf(px_), fy0 = floorf(py_);
    int xi0 = (int)fx0, yi0 = (int)fy0;
    int xi1 = min(xi0 + 1, WW - 1), yi1 = min(yi0 + 1, HH - 1);
    float wx = px_ - fx0, wy = py_ - fy0;
    float w00 = (1.f - wx) * (1.f - wy), w01 = wx * (1.f - wy);
    float w10 = (1.f - wx) * wy, w11 = wx * wy;

    const uint32* a = (const uint32*)(f2 + ((size_t)yi0 * WW + xi0) * 32);
    const uint32* b = (const uint32*)(f2 + ((size_t)yi0 * WW + xi1) * 32);
    const uint32* c = (const uint32*)(f2 + ((size_t)yi1 * WW + xi0) * 32);
    const uint32* d = (const uint32*)(f2 + ((size_t)yi1 * WW + xi1) * 32);
    uint32 ov[16];
#pragma unroll
    for (int i = 0; i < 16; ++i) {
        uint32 wa = a[i], wb = b[i], wc = c[i], wd = d[i];
        float lo = __uint_as_float(wa << 16) * w00 + __uint_as_float(wb << 16) * w01 +
                   __uint_as_float(wc << 16) * w10 + __uint_as_float(wd << 16) * w11;
        float hi = __uint_as_float(wa & 0xffff0000u) * w00 + __uint_as_float(wb & 0xffff0000u) * w01 +
                   __uint_as_float(wc & 0xffff0000u) * w10 + __uint_as_float(wd & 0xffff0000u) * w11;
        ov[i] = ((uint32)f2bf(hi) << 16) | f2bf(lo);
    }
    uint32* o = (uint32*)(outp + (size_t)idx * 32);
#pragma unroll
    for (int i = 0; i < 16; ++i) o[i] = ov[i];
}

// ---------------------------------------------------------------------------
// Cost volume via MFMA. Block 256 = 4 waves; wave wv handles one y-row
// (y = blockIdx.y*4 + wv) x 16-px tile x all 9 dy. Two 16x16x32 GEMMs per dy.
// grid.z = batch (separate strides per buffer).
// ---------------------------------------------------------------------------
__global__ __launch_bounds__(256) void cost_mfma_k(
    const ushort* __restrict__ f1, const ushort* __restrict__ f2w,
    const float* __restrict__ flow, ushort* __restrict__ hb,
    long f1S, long f2wS, long hbS, long flowS)
{
    const int tid = threadIdx.x;
    const int wv = tid >> 6;
    const int lane = tid & 63;
    const int c = lane & 15;
    const int quad = lane >> 4;
    const int x0 = blockIdx.x * 16;
    const int y = blockIdx.y * 4 + wv;
    f1 += (size_t)blockIdx.z * f1S;
    f2w += (size_t)blockIdx.z * f2wS;
    hb += (size_t)blockIdx.z * hbS;
    flow += (size_t)blockIdx.z * flowS;

    const bf16x8 a = *(const bf16x8*)(f1 + ((size_t)y * WW + x0 + c) * 32 + quad * 8);

    const int xc0 = min(max(x0 - 4 + c, 0), WW - 1);
    const int xc1 = min(max(x0 + 12 + c, 0), WW - 1);

    ushort* hrow = hb + ((size_t)y * WW + x0) * 96;

#pragma unroll 1
    for (int dyi = 0; dyi < 9; ++dyi) {
        const int ys = min(max(y + dyi - 4, 0), HH - 1);
        const bf16x8 b0 = *(const bf16x8*)(f2w + ((size_t)ys * WW + xc0) * 32 + quad * 8);
        const bf16x8 b1 = *(const bf16x8*)(f2w + ((size_t)ys * WW + xc1) * 32 + quad * 8);
        f32x4 s0 = __builtin_amdgcn_mfma_f32_16x16x32_bf16(
            a, b0, (f32x4){0.f, 0.f, 0.f, 0.f}, 0, 0, 0);
        f32x4 s1 = __builtin_amdgcn_mfma_f32_16x16x32_bf16(
            a, b1, (f32x4){0.f, 0.f, 0.f, 0.f}, 0, 0, 0);

        ushort* hq = hrow + dyi * 9;
#pragma unroll
        for (int r = 0; r < 4; ++r) {
            const int m = quad * 4 + r;
            const int d0 = c - m;
            const int d1 = c + 16 - m;
            if (d0 >= 0 && d0 <= 8) hq[(size_t)m * 96 + d0] = f2bf(s0[r]);
            if (d1 <= 8) hq[(size_t)m * 96 + d1] = f2bf(s1[r]);
        }
    }

    if (lane < 16) {
        const int px = y * WW + x0 + lane;
        ushort* hq = hb + (size_t)px * 96;
        hq[81] = f2bf(flow[px]);
        hq[82] = f2bf(flow[px + HW]);
#pragma unroll
        for (int ch = 83; ch < 96; ++ch) hq[ch] = 0;
    }
}

// ---------------------------------------------------------------------------
// rconv4: 64 -> 2, + initial_flow residual, fp32 NCHW output. grid.y = batch.
// ---------------------------------------------------------------------------
__global__ __launch_bounds__(256) void rconv4_k(
    const ushort* __restrict__ in, const float* __restrict__ w,
    const float* __restrict__ bias, const float* __restrict__ flow,
    float* __restrict__ out, long inStride, long ioStride)
{
    __shared__ float wl[1152];
    for (int i = threadIdx.x; i < 1152; i += 256) wl[i] = w[i];
    __syncthreads();
    in += (size_t)blockIdx.y * inStride;
    flow += (size_t)blockIdx.y * ioStride;
    out += (size_t)blockIdx.y * ioStride;
    int px = blockIdx.x * 256 + threadIdx.x;
    if (px >= HW) return;
    int y = px / WW, x = px - y * WW;
    float a0 = bias[0], a1 = bias[1];
    for (int ky = 0; ky < 3; ++ky) {
        int gy = y + ky - 1;
        if (gy < 0 || gy >= HH) continue;
        for (int kx = 0; kx < 3; ++kx) {
            int gx = x + kx - 1;
            if (gx < 0 || gx >= WW) continue;
            const uint32* p = (const uint32*)(in + ((size_t)gy * WW + gx) * 64);
            int tap = ky * 3 + kx;
#pragma unroll
            for (int i = 0; i < 32; ++i) {
                uint32 wv = p[i];
                float lo = __uint_as_float(wv << 16);
                float hi = __uint_as_float(wv & 0xffff0000u);
                a0 = fmaf(lo, wl[(2 * i) * 9 + tap], a0);
                a0 = fmaf(hi, wl[(2 * i + 1) * 9 + tap], a0);
                a1 = fmaf(lo, wl[576 + (2 * i) * 9 + tap], a1);
                a1 = fmaf(hi, wl[576 + (2 * i + 1) * 9 + tap], a1);
            }
        }
    }
    out[px] = flow[px] + a0;
    out[px + HW] = flow[px + HW] + a1;
}

extern "C" void kernel_launch(void* const* d_in, const int* in_sizes, int n_in,
                              void* d_out, int out_size, void* d_ws, size_t ws_size,
                              hipStream_t stream)
{
    (void)in_sizes; (void)n_in; (void)out_size;
    const float* feat1 = (const float*)d_in[0];
    const float* feat2 = (const float*)d_in[1];
    const float* iflow = (const float*)d_in[2];
    const float* fW1 = (const float*)d_in[3];  const float* fb1 = (const float*)d_in[4];
    const float* fW2 = (const float*)d_in[5];  const float* fb2 = (const float*)d_in[6];
    const float* fW3 = (const float*)d_in[7];  const float* fb3 = (const float*)d_in[8];
    const float* rW1 = (const float*)d_in[9];  const float* rb1 = (const float*)d_in[10];
    const float* rW2 = (const float*)d_in[11]; const float* rb2 = (const float*)d_in[12];
    const float* rW3 = (const float*)d_in[13]; const float* rb3 = (const float*)d_in[14];
    const float* rW4 = (const float*)d_in[15]; const float* rb4 = (const float*)d_in[16];
    float* out = (float*)d_out;

    // Workspace (bf16 elems): [packed weights][XA nb*128P][XB nb*128P][F nb*64P]
    // Aliases: F2W = XA (nb*32P), Hb = XA+nb*32P (nb*96P), R1 = XB,
    // R2 = XA, R3 = F. Live ranges disjoint.
    const size_t P = (size_t)HW;
    const size_t WTOT = (size_t)9 * (64 * 64 + 64 * 32 + 96 * 128 + 128 * 128 + 128 * 64);
    ushort* ws0 = (ushort*)d_ws;
    ushort* wp2  = ws0;
    ushort* wp3  = wp2 + 9 * 64 * 64;
    ushort* wpr1 = wp3 + 9 * 64 * 32;
    ushort* wpr2 = wpr1 + 9 * 96 * 128;
    ushort* wpr3 = wpr2 + 9 * 128 * 128;
    ushort* arena = ws0 + WTOT;

    const bool merged = ws_size >= (WTOT + 640 * P) * sizeof(ushort);
    const int nb = merged ? 2 : 1;
    const int nloop = merged ? 1 : 2;

    ushort* XA = arena;
    ushort* XB = XA + (size_t)(nb * 128) * P;
    ushort* F  = XB + (size_t)(nb * 128) * P;
    ushort* F2W = XA;
    ushort* Hb  = XA + (size_t)(nb * 32) * P;
    ushort* R1  = XB;
    ushort* R2  = XA;
    ushort* R3  = F;

    const dim3 blk(256);
    pack_all_k<<<dim3((9 * 128 * 128 + 255) / 256), blk, 0, stream>>>(
        fW2, fW3, rW1, rW2, rW3, wp2, wp3, wpr1, wpr2, wpr3);

    const dim3 gConvX(WW / 16, HH / 8, nb * 2);  // extractor convs (b x img)
    const dim3 gConvB(WW / 16, HH / 8, nb);      // head convs (b)
    const dim3 gF1(WW / 16, HH / 2, nb * 2);
    const dim3 gCost(WW / 16, HH / 4, nb);
    const int gPix = (HW + 255) / 256;

    for (int lb = 0; lb < nloop; ++lb) {
        const float* f1in = feat1 + (size_t)lb * 3 * P;
        const float* f2in = feat2 + (size_t)lb * 3 * P;
        const float* flw  = iflow + (size_t)lb * 2 * P;
        float* outb = out + (size_t)lb * 2 * P;

        // Extractor, both images fused (z = b*2+img)
        fconv1_k<<<gF1, blk, 0, stream>>>(f1in, f2in, fW1, fb1, XA, 3 * (long)P, 64 * (long)P);
        convmfma_k<64, 64, 1><<<gConvX, blk, 0, stream>>>(XA, wp2, fb2, XB, 64 * (long)P, 64 * (long)P);
        convmfma_k<64, 32, 1><<<gConvX, blk, 0, stream>>>(XB, wp3, fb3, F, 64 * (long)P, 32 * (long)P);

        // Warp f2 features (F2[b] = F + (2b+1)*32P, batch stride 64P)
        warp_k<<<dim3(gPix, nb), blk, 0, stream>>>(F + 32 * P, flw, F2W,
                                                   64 * (long)P, 2 * (long)P, 32 * (long)P);

        // Cost volume (+ flow + zero pad) -> Hb (96ch NHWC)
        cost_mfma_k<<<gCost, blk, 0, stream>>>(F, F2W, flw, Hb,
                                               64 * (long)P, 32 * (long)P, 96 * (long)P, 2 * (long)P);

        // Refinement head
        convmfma_k<96, 128, 1><<<gConvB, blk, 0, stream>>>(Hb, wpr1, rb1, R1, 96 * (long)P, 128 * (long)P);
        convmfma_k<128, 128, 1><<<gConvB, blk, 0, stream>>>(R1, wpr2, rb2, R2, 128 * (long)P, 128 * (long)P);
        convmfma_k<128, 64, 1><<<gConvB, blk, 0, stream>>>(R2, wpr3, rb3, R3, 128 * (long)P, 64 * (long)P);
        rconv4_k<<<dim3(gPix, nb), blk, 0, stream>>>(R3, rW4, rb4, flw, outb, 64 * (long)P, 2 * (long)P);
    }
}